// Round 12
// baseline (130.324 us; speedup 1.0000x reference)
//
#include <hip/hip_runtime.h>
#include <hip/hip_bf16.h>

#define B_ 4
#define N_ 16384
#define K_ 16
#define NEG 0.2f
#define EPSBN 1e-5f
#define INV_SIG2 2500.0f

typedef unsigned short u16;
typedef unsigned int   u32;
typedef __attribute__((ext_vector_type(8))) short short8;
typedef __attribute__((ext_vector_type(4))) float f32x4;

__device__ __forceinline__ float bf2f(u16 h){
  return __uint_as_float(((u32)h) << 16);
}
__device__ __forceinline__ u16 f2bf(float f){
  u32 x = __float_as_uint(f);
  x += 0x7fffu + ((x >> 16) & 1u);
  return (u16)(x >> 16);
}

// u/v layout: UNSPLIT [B][N][64] u16 (128B rows).
// wmax/wmin layout: split [half][B][N][32] u16 (k4 reads this).

// ---------------- K0: wbf [j][o][c]; weA [o][c]; zero stats ----------------------
__global__ void k0_wprep(const float* __restrict__ wconv, u16* __restrict__ wbf,
                         const float* __restrict__ we, u16* __restrict__ weA,
                         float* __restrict__ stats){
  const int idx = blockIdx.x * 256 + threadIdx.x;
  if (idx < 128) stats[idx] = 0.f;
  if (idx < 9*128*64){
    const int j = idx >> 13;
    const int rem = idx & 8191;
    const int o = rem >> 6, c = rem & 63;
    wbf[idx] = f2bf(wconv[(o*64 + c)*9 + j]);
  } else if (idx < 9*128*64 + 128*64){
    const int t = idx - 9*128*64;
    const int o = t >> 6, c = t & 63;
    float w;
    if (o < 64) w = we[o*128 + c] - we[o*128 + 64 + c];
    else        w = we[(o-64)*128 + 64 + c];
    weA[t] = f2bf(w);
  }
}

// ---------------- K1 v3: MFMA GEMM; u/v stored unsplit [B][N][64] ----------------
__global__ __launch_bounds__(256) void k1_uv(const float* __restrict__ x,
                                             const u16* __restrict__ weA,
                                             u16* __restrict__ uo,
                                             u16* __restrict__ vo){
  const int n0 = blockIdx.x * 64;
  const int b  = blockIdx.y;
  const int tid = threadIdx.x;
  const int w = tid >> 6, lane = tid & 63;
  const int r15 = lane & 15, kg = lane >> 4;

  __shared__ u16 tl[128*72];   // [o][n] stride 72 -> 18.4 KB

  short8 a[2][2];
  #pragma unroll
  for (int of = 0; of < 2; ++of)
    #pragma unroll
    for (int kh = 0; kh < 2; ++kh)
      a[of][kh] = *(const short8*)&weA[(w*32 + of*16 + r15)*64 + kg*8 + kh*32];

  const float* xb = x + (size_t)b*64*N_ + n0 + r15;
  f32x4 acc[2][4];
  const f32x4 zero = {0.f, 0.f, 0.f, 0.f};

  #pragma unroll
  for (int nf = 0; nf < 4; ++nf){
    short8 bq[2];
    #pragma unroll
    for (int kh = 0; kh < 2; ++kh){
      float f[8];
      #pragma unroll
      for (int e = 0; e < 8; ++e)
        f[e] = xb[(size_t)(kg*8 + kh*32 + e)*N_ + nf*16];
      union { short8 s; u32 u[4]; } bb;
      #pragma unroll
      for (int e2 = 0; e2 < 4; ++e2)
        bb.u[e2] = (u32)f2bf(f[e2*2]) | ((u32)f2bf(f[e2*2+1]) << 16);
      bq[kh] = bb.s;
    }
    #pragma unroll
    for (int of = 0; of < 2; ++of){
      f32x4 p = __builtin_amdgcn_mfma_f32_16x16x32_bf16(a[of][0], bq[0], zero, 0, 0, 0);
      acc[of][nf] = __builtin_amdgcn_mfma_f32_16x16x32_bf16(a[of][1], bq[1], p, 0, 0, 0);
    }
  }

  #pragma unroll
  for (int of = 0; of < 2; ++of)
    #pragma unroll
    for (int rr = 0; rr < 4; ++rr){
      const int o = w*32 + of*16 + kg*4 + rr;
      #pragma unroll
      for (int nf = 0; nf < 4; ++nf)
        tl[o*72 + nf*16 + r15] = f2bf(acc[of][nf][rr]);
    }
  __syncthreads();

  // store unsplit: thread (arr, nh, n) writes channels nh*32..+32 of row n
  const int arr = tid >> 7, nh = (tid >> 6) & 1, n = tid & 63;
  const int ro = arr*64 + nh*32;
  u32 pk[16];
  #pragma unroll
  for (int cc = 0; cc < 16; ++cc){
    const u16 lo = tl[(ro + cc*2    )*72 + n];
    const u16 hi = tl[(ro + cc*2 + 1)*72 + n];
    pk[cc] = (u32)lo | ((u32)hi << 16);
  }
  u16* dst = (arr ? vo : uo) + ((size_t)(b*N_ + n0 + n))*64 + nh*32;
  *(uint4*)(dst +  0) = make_uint4(pk[0],  pk[1],  pk[2],  pk[3]);
  *(uint4*)(dst +  8) = make_uint4(pk[4],  pk[5],  pk[6],  pk[7]);
  *(uint4*)(dst + 16) = make_uint4(pk[8],  pk[9],  pk[10], pk[11]);
  *(uint4*)(dst + 24) = make_uint4(pk[12], pk[13], pk[14], pk[15]);
}

// ---------------- K2 v10: dwordx2 gathers, unsplit rows --------------------------
// 2048 blocks x 256 thr, XCD batch pinning. lane = kk*16+cg: kk = k-slot,
// cg = channel-quad (4 ch = 8B). One instr = 4 rows x 128B; 8 instrs/point
// (vs 16 in v8), same line count — discriminates instr-rate vs line-rate limit.
__global__ __launch_bounds__(256) void k2_gather(const u16* __restrict__ uo,
                                                 const u16* __restrict__ vo,
                                                 const int* __restrict__ eidx,
                                                 u16* __restrict__ wmaxo,
                                                 u16* __restrict__ wmino,
                                                 float* __restrict__ stats){
  const int bid = blockIdx.x;
  const int xcd = bid & 7;
  const int b   = xcd >> 1;
  const int n0  = ((bid >> 3) + (xcd & 1)*256) * 32;
  const int tid = threadIdx.x;
  const int wid = tid >> 6, lane = tid & 63;
  const int kk = lane >> 4, cg = lane & 15;
  const int nb = n0 + wid*8;                 // wave's 8 points
  const u16* ub = uo + (size_t)b*N_*64;
  const u16* vb = vo + (size_t)b*N_*64;

  __shared__ int eL[4][2][128];              // per-wave eidx copy (4KB)
  __shared__ float redS[4][64], redQ[4][64];

  const int* e0 = eidx + (b*N_ + nb)*K_;               // j (neighbor -> v)
  const int* e1 = eidx + B_*N_*K_ + (b*N_ + nb)*K_;    // i (center   -> u)
  if (lane < 32) *(int4*)&eL[wid][0][lane*4]      = *(const int4*)(e0 + lane*4);
  else           *(int4*)&eL[wid][1][(lane-32)*4] = *(const int4*)(e1 + (lane-32)*4);
  __syncthreads();

  float sm[4] = {0.f,0.f,0.f,0.f}, sq[4] = {0.f,0.f,0.f,0.f};

  for (int p = 0; p < 8; ++p){
    int ji[4], ii[4];
    #pragma unroll
    for (int s = 0; s < 4; ++s){
      ji[s] = eL[wid][0][p*16 + s*4 + kk];
      ii[s] = eL[wid][1][p*16 + s*4 + kk];
    }
    uint2 ua[4], va[4];
    #pragma unroll
    for (int s = 0; s < 4; ++s){
      ua[s] = *(const uint2*)&ub[(size_t)ii[s]*64 + cg*4];
      va[s] = *(const uint2*)&vb[(size_t)ji[s]*64 + cg*4];
    }
    float h[4][4];   // [s][ch]
    #pragma unroll
    for (int s = 0; s < 4; ++s){
      h[s][0] = __uint_as_float(ua[s].x << 16)         + __uint_as_float(va[s].x << 16);
      h[s][1] = __uint_as_float(ua[s].x & 0xffff0000u) + __uint_as_float(va[s].x & 0xffff0000u);
      h[s][2] = __uint_as_float(ua[s].y << 16)         + __uint_as_float(va[s].y << 16);
      h[s][3] = __uint_as_float(ua[s].y & 0xffff0000u) + __uint_as_float(va[s].y & 0xffff0000u);
    }
    float mx[4], mn[4];
    #pragma unroll
    for (int c = 0; c < 4; ++c){
      mx[c] = fmaxf(fmaxf(h[0][c],h[1][c]), fmaxf(h[2][c],h[3][c]));
      mn[c] = fminf(fminf(h[0][c],h[1][c]), fminf(h[2][c],h[3][c]));
      sm[c] += (h[0][c]+h[1][c]) + (h[2][c]+h[3][c]);
      sq[c] = fmaf(h[0][c],h[0][c], fmaf(h[1][c],h[1][c],
              fmaf(h[2][c],h[2][c], fmaf(h[3][c],h[3][c], sq[c]))));
      mx[c] = fmaxf(mx[c], __shfl_xor(mx[c],16)); mx[c] = fmaxf(mx[c], __shfl_xor(mx[c],32));
      mn[c] = fminf(mn[c], __shfl_xor(mn[c],16)); mn[c] = fminf(mn[c], __shfl_xor(mn[c],32));
    }
    const int n = nb + p;
    if (kk == 0){
      const int c0 = cg*4;              // global channel base
      const int hh = c0 >> 5;           // wmax/wmin half (split layout for k4)
      u16* wm = wmaxo + ((size_t)(hh*B_ + b)*N_ + n)*32 + (c0 & 31);
      u16* wn = wmino + ((size_t)(hh*B_ + b)*N_ + n)*32 + (c0 & 31);
      uint2 pm, pn;
      pm.x = (u32)f2bf(mx[0]) | ((u32)f2bf(mx[1]) << 16);
      pm.y = (u32)f2bf(mx[2]) | ((u32)f2bf(mx[3]) << 16);
      pn.x = (u32)f2bf(mn[0]) | ((u32)f2bf(mn[1]) << 16);
      pn.y = (u32)f2bf(mn[2]) | ((u32)f2bf(mn[3]) << 16);
      *(uint2*)wm = pm;
      *(uint2*)wn = pn;
    }
  }

  #pragma unroll
  for (int c = 0; c < 4; ++c){
    sm[c] += __shfl_xor(sm[c],16); sm[c] += __shfl_xor(sm[c],32);
    sq[c] += __shfl_xor(sq[c],16); sq[c] += __shfl_xor(sq[c],32);
  }
  if (kk == 0){
    #pragma unroll
    for (int c = 0; c < 4; ++c){
      redS[wid][cg*4 + c] = sm[c];
      redQ[wid][cg*4 + c] = sq[c];
    }
  }
  __syncthreads();
  if (tid < 64){
    atomicAdd(&stats[tid], redS[0][tid]+redS[1][tid]+redS[2][tid]+redS[3][tid]);
  } else if (tid < 128){
    const int c = tid - 64;
    atomicAdd(&stats[64 + c], redQ[0][c]+redQ[1][c]+redQ[2][c]+redQ[3][c]);
  }
}

// ---------------- K4 v2: MFMA weighted conv, n-tile 64 (UNCHANGED) ---------------
__global__ __launch_bounds__(256) void k4_mfma(const u16* __restrict__ wmaxo,
                                               const u16* __restrict__ wmino,
                                               const float* __restrict__ stats,
                                               const float* __restrict__ gamma,
                                               const float* __restrict__ beta,
                                               const float* __restrict__ coords,
                                               const u16* __restrict__ wbf,
                                               const float* __restrict__ bconv,
                                               float* __restrict__ out){
  const int n0 = blockIdx.x * 64;
  const int b  = blockIdx.y;
  const int tid = threadIdx.x;
  const int w = tid >> 6, lane = tid & 63;
  const int r15 = lane & 15, kg = lane >> 4;

  __shared__ u16 hl[72*72];     // [m_local][c], row stride 72 (pad) -> 10.4 KB
  __shared__ float wgt[9*64];   // [j][n] Gaussian weights
  __shared__ float sctl[128];   // BN affine

  if (tid < 64){
    const float inv = 1.0f / (float)(B_*N_*K_);
    const float mean = stats[tid] * inv;
    const float var  = stats[64+tid] * inv - mean*mean;
    const float s = gamma[tid] * rsqrtf(var + EPSBN);
    sctl[tid] = s;
    sctl[64+tid] = beta[tid] - mean*s;
  }
  __syncthreads();

  {
    const int c = tid & 63;
    const float s = sctl[c], t = sctl[64+c];
    const u16* src = ((s >= 0.f) ? wmaxo : wmino)
                   + ((size_t)((c >> 5)*B_ + b))*N_*32 + (c & 31);
    #pragma unroll
    for (int it = 0; it < 18; ++it){
      const int ml = (tid >> 6) + it*4;
      const int m = n0 - 4 + ml;
      float hv = 0.f;
      if (m >= 0 && m < N_){
        hv = fmaf(s, bf2f(src[(size_t)m*32]), t);
        hv = (hv >= 0.f) ? hv : NEG*hv;
      }
      hl[ml*72 + c] = f2bf(hv);
    }
  }
  for (int idx = tid; idx < 576; idx += 256){
    const int j = idx >> 6, n = idx & 63;
    const int mc = n0 + n, mt = mc + j - 4;
    float wv = 0.f;
    if (mt >= 0 && mt < N_){
      float d2 = 0.f;
      #pragma unroll
      for (int d = 0; d < 3; ++d){
        const float dd = coords[(b*3+d)*N_ + mt] - coords[(b*3+d)*N_ + mc];
        d2 = fmaf(dd, dd, d2);
      }
      wv = __expf(-INV_SIG2 * d2);
    }
    wgt[idx] = wv;
  }
  __syncthreads();

  const u16* abase = wbf + ((w*32 + r15)*64 + kg*8);
  const u16* hbase = &hl[r15*72 + kg*8];
  f32x4 acc[2][4] = {};
  const f32x4 zero = {0.f, 0.f, 0.f, 0.f};

  for (int j = 0; j < 9; ++j){
    float wj[4];
    #pragma unroll
    for (int nf = 0; nf < 4; ++nf) wj[nf] = wgt[j*64 + nf*16 + r15];
    short8 bfr[4][2];
    #pragma unroll
    for (int nf = 0; nf < 4; ++nf){
      bfr[nf][0] = *(const short8*)&hbase[(nf*16 + j)*72];
      bfr[nf][1] = *(const short8*)&hbase[(nf*16 + j)*72 + 32];
    }
    #pragma unroll
    for (int of = 0; of < 2; ++of){
      const short8 a0 = *(const short8*)&abase[j*8192 + of*1024];
      const short8 a1 = *(const short8*)&abase[j*8192 + of*1024 + 32];
      #pragma unroll
      for (int nf = 0; nf < 4; ++nf){
        f32x4 p = __builtin_amdgcn_mfma_f32_16x16x32_bf16(a0, bfr[nf][0], zero, 0, 0, 0);
        p = __builtin_amdgcn_mfma_f32_16x16x32_bf16(a1, bfr[nf][1], p, 0, 0, 0);
        #pragma unroll
        for (int r = 0; r < 4; ++r)
          acc[of][nf][r] = fmaf(wj[nf], p[r], acc[of][nf][r]);
      }
    }
  }

  #pragma unroll
  for (int of = 0; of < 2; ++of){
    #pragma unroll
    for (int r = 0; r < 4; ++r){
      const int o = w*32 + of*16 + kg*4 + r;
      const float bs = bconv[o];
      float* dst = &out[(size_t)(b*128 + o)*N_ + n0 + r15];
      #pragma unroll
      for (int nf = 0; nf < 4; ++nf)
        dst[nf*16] = acc[of][nf][r] + bs;
    }
  }
}

extern "C" void kernel_launch(void* const* d_in, const int* in_sizes, int n_in,
                              void* d_out, int out_size, void* d_ws, size_t ws_size,
                              hipStream_t stream){
  const float* x      = (const float*)d_in[0];
  const float* coords = (const float*)d_in[1];
  const int*   eidx   = (const int*)  d_in[2];
  const float* we     = (const float*)d_in[3];
  const float* gamma  = (const float*)d_in[4];
  const float* beta   = (const float*)d_in[5];
  const float* wconv  = (const float*)d_in[6];
  const float* bconv  = (const float*)d_in[7];
  float* out = (float*)d_out;
  char* ws = (char*)d_ws;
  // ws layout (bytes): u[8.39MB] v[8.39MB] wmax[8.39MB] wmin[8.39MB] stats[512]
  //                    (pad 512) wbf[147KB] weA[16KB]
  u16* u     = (u16*)(ws);
  u16* v     = (u16*)(ws + 8388608);
  u16* wmax_ = (u16*)(ws + 16777216);
  u16* wmin_ = (u16*)(ws + 25165824);
  float* stats = (float*)(ws + 33554432);
  u16* wbf     = (u16*)(ws + 33555456);
  u16* weA     = (u16*)(ws + 33555456 + 147456);

  k0_wprep<<<320, 256, 0, stream>>>(wconv, wbf, we, weA, stats);
  k1_uv<<<dim3(N_/64, B_), 256, 0, stream>>>(x, weA, u, v);
  k2_gather<<<2048, 256, 0, stream>>>(u, v, eidx, wmax_, wmin_, stats);
  k4_mfma<<<dim3(N_/64, B_), 256, 0, stream>>>(wmax_, wmin_, stats, gamma, beta,
                                               coords, wbf, bconv, out);
}

// Round 13
// 113.388 us; speedup vs baseline: 1.1494x; 1.1494x over previous
//
#include <hip/hip_runtime.h>
#include <hip/hip_bf16.h>

#define B_ 4
#define N_ 16384
#define K_ 16
#define NEG 0.2f
#define EPSBN 1e-5f
#define INV_SIG2 2500.0f

typedef unsigned short u16;
typedef unsigned int   u32;
typedef __attribute__((ext_vector_type(8))) short short8;
typedef __attribute__((ext_vector_type(4))) float f32x4;

__device__ __forceinline__ float bf2f(u16 h){
  return __uint_as_float(((u32)h) << 16);
}
__device__ __forceinline__ u16 f2bf(float f){
  u32 x = __float_as_uint(f);
  x += 0x7fffu + ((x >> 16) & 1u);
  return (u16)(x >> 16);
}

// u/v/wmax/wmin layout: split [half][B][N][32] u16 — (batch, channel-half)
// partition = 2MB u+v -> fits one XCD's 4MB L2 (round-7 win, round-12 revert).

// ---------------- K0: wbf [j][o][c]; weA [o][c]; zero stats ----------------------
__global__ void k0_wprep(const float* __restrict__ wconv, u16* __restrict__ wbf,
                         const float* __restrict__ we, u16* __restrict__ weA,
                         float* __restrict__ stats){
  const int idx = blockIdx.x * 256 + threadIdx.x;
  if (idx < 128) stats[idx] = 0.f;
  if (idx < 9*128*64){
    const int j = idx >> 13;
    const int rem = idx & 8191;
    const int o = rem >> 6, c = rem & 63;
    wbf[idx] = f2bf(wconv[(o*64 + c)*9 + j]);
  } else if (idx < 9*128*64 + 128*64){
    const int t = idx - 9*128*64;
    const int o = t >> 6, c = t & 63;
    float w;
    if (o < 64) w = we[o*128 + c] - we[o*128 + 64 + c];
    else        w = we[(o-64)*128 + 64 + c];
    weA[t] = f2bf(w);
  }
}

// ---------------- K1 v2: MFMA GEMM [u;v](128 x n) = weA(128x64) * x(64 x n) ------
// split-layout stores (round-9 version, reverted)
__global__ __launch_bounds__(256) void k1_uv(const float* __restrict__ x,
                                             const u16* __restrict__ weA,
                                             u16* __restrict__ uo,
                                             u16* __restrict__ vo){
  const int n0 = blockIdx.x * 64;
  const int b  = blockIdx.y;
  const int tid = threadIdx.x;
  const int w = tid >> 6, lane = tid & 63;
  const int r15 = lane & 15, kg = lane >> 4;

  __shared__ u16 tl[128*72];   // [o][n] stride 72 -> 18.4 KB

  short8 a[2][2];
  #pragma unroll
  for (int of = 0; of < 2; ++of)
    #pragma unroll
    for (int kh = 0; kh < 2; ++kh)
      a[of][kh] = *(const short8*)&weA[(w*32 + of*16 + r15)*64 + kg*8 + kh*32];

  const float* xb = x + (size_t)b*64*N_ + n0 + r15;
  f32x4 acc[2][4];
  const f32x4 zero = {0.f, 0.f, 0.f, 0.f};

  #pragma unroll
  for (int nf = 0; nf < 4; ++nf){
    short8 bq[2];
    #pragma unroll
    for (int kh = 0; kh < 2; ++kh){
      float f[8];
      #pragma unroll
      for (int e = 0; e < 8; ++e)
        f[e] = xb[(size_t)(kg*8 + kh*32 + e)*N_ + nf*16];
      union { short8 s; u32 u[4]; } bb;
      #pragma unroll
      for (int e2 = 0; e2 < 4; ++e2)
        bb.u[e2] = (u32)f2bf(f[e2*2]) | ((u32)f2bf(f[e2*2+1]) << 16);
      bq[kh] = bb.s;
    }
    #pragma unroll
    for (int of = 0; of < 2; ++of){
      f32x4 p = __builtin_amdgcn_mfma_f32_16x16x32_bf16(a[of][0], bq[0], zero, 0, 0, 0);
      acc[of][nf] = __builtin_amdgcn_mfma_f32_16x16x32_bf16(a[of][1], bq[1], p, 0, 0, 0);
    }
  }

  #pragma unroll
  for (int of = 0; of < 2; ++of)
    #pragma unroll
    for (int rr = 0; rr < 4; ++rr){
      const int o = w*32 + of*16 + kg*4 + rr;
      #pragma unroll
      for (int nf = 0; nf < 4; ++nf)
        tl[o*72 + nf*16 + r15] = f2bf(acc[of][nf][rr]);
    }
  __syncthreads();

  const int arr = tid >> 7, half = (tid >> 6) & 1, n = tid & 63;
  const int ro = arr*64 + half*32;
  u32 pk[16];
  #pragma unroll
  for (int cc = 0; cc < 16; ++cc){
    const u16 lo = tl[(ro + cc*2    )*72 + n];
    const u16 hi = tl[(ro + cc*2 + 1)*72 + n];
    pk[cc] = (u32)lo | ((u32)hi << 16);
  }
  u16* dst = (arr ? vo : uo) + ((size_t)(half*B_ + b)*N_ + n0 + n)*32;
  *(uint4*)(dst +  0) = make_uint4(pk[0],  pk[1],  pk[2],  pk[3]);
  *(uint4*)(dst +  8) = make_uint4(pk[4],  pk[5],  pk[6],  pk[7]);
  *(uint4*)(dst + 16) = make_uint4(pk[8],  pk[9],  pk[10], pk[11]);
  *(uint4*)(dst + 24) = make_uint4(pk[12], pk[13], pk[14], pk[15]);
}

// ---------------- K2 v8 (round-9 best, reverted verbatim) ------------------------
__global__ __launch_bounds__(256) void k2_gather(const u16* __restrict__ uo,
                                                 const u16* __restrict__ vo,
                                                 const int* __restrict__ eidx,
                                                 u16* __restrict__ wmaxo,
                                                 u16* __restrict__ wmino,
                                                 float* __restrict__ stats){
  const int bid = blockIdx.x;
  const int p8  = bid & 7;
  const int b   = p8 >> 1;
  const int h   = p8 & 1;
  const int n0  = (bid >> 3) * 32;
  const int tid = threadIdx.x;
  const int wid = tid >> 6, lane = tid & 63;
  const int kk = lane >> 4, cg = lane & 15;
  const int nb = n0 + wid*8;                 // wave's 8 points
  const size_t pbase = ((size_t)(h*B_ + b))*N_*32;
  const u16* ub = uo + pbase;
  const u16* vb = vo + pbase;

  __shared__ int eL[4][2][128];              // per-wave eidx copy (4KB)
  __shared__ float redS[4][32], redQ[4][32];

  const int* e0 = eidx + (b*N_ + nb)*K_;               // j (neighbor -> v)
  const int* e1 = eidx + B_*N_*K_ + (b*N_ + nb)*K_;    // i (center   -> u)
  if (lane < 32) *(int4*)&eL[wid][0][lane*4]      = *(const int4*)(e0 + lane*4);
  else           *(int4*)&eL[wid][1][(lane-32)*4] = *(const int4*)(e1 + (lane-32)*4);
  __syncthreads();

  float s0=0.f, s1=0.f, q0=0.f, q1=0.f;

  for (int p = 0; p < 8; ++p){
    int ji[4], ii[4];
    #pragma unroll
    for (int s = 0; s < 4; ++s){
      ji[s] = eL[wid][0][p*16 + s*4 + kk];
      ii[s] = eL[wid][1][p*16 + s*4 + kk];
    }
    u32 ua[4], va[4];
    #pragma unroll
    for (int s = 0; s < 4; ++s){
      ua[s] = *(const u32*)&ub[(size_t)ii[s]*32 + cg*2];
      va[s] = *(const u32*)&vb[(size_t)ji[s]*32 + cg*2];
    }
    float hL[4], hH[4];
    #pragma unroll
    for (int s = 0; s < 4; ++s){
      hL[s] = __uint_as_float(ua[s] << 16)         + __uint_as_float(va[s] << 16);
      hH[s] = __uint_as_float(ua[s] & 0xffff0000u) + __uint_as_float(va[s] & 0xffff0000u);
    }
    float mx0 = fmaxf(fmaxf(hL[0],hL[1]), fmaxf(hL[2],hL[3]));
    float mn0 = fminf(fminf(hL[0],hL[1]), fminf(hL[2],hL[3]));
    float mx1 = fmaxf(fmaxf(hH[0],hH[1]), fmaxf(hH[2],hH[3]));
    float mn1 = fminf(fminf(hH[0],hH[1]), fminf(hH[2],hH[3]));
    s0 += (hL[0]+hL[1]) + (hL[2]+hL[3]);
    s1 += (hH[0]+hH[1]) + (hH[2]+hH[3]);
    q0 = fmaf(hL[0],hL[0], fmaf(hL[1],hL[1], fmaf(hL[2],hL[2], fmaf(hL[3],hL[3], q0))));
    q1 = fmaf(hH[0],hH[0], fmaf(hH[1],hH[1], fmaf(hH[2],hH[2], fmaf(hH[3],hH[3], q1))));
    mx0 = fmaxf(mx0, __shfl_xor(mx0, 16)); mx0 = fmaxf(mx0, __shfl_xor(mx0, 32));
    mx1 = fmaxf(mx1, __shfl_xor(mx1, 16)); mx1 = fmaxf(mx1, __shfl_xor(mx1, 32));
    mn0 = fminf(mn0, __shfl_xor(mn0, 16)); mn0 = fminf(mn0, __shfl_xor(mn0, 32));
    mn1 = fminf(mn1, __shfl_xor(mn1, 16)); mn1 = fminf(mn1, __shfl_xor(mn1, 32));
    const int n = nb + p;
    if (lane < 16){
      const u32 pm = (u32)f2bf(mx0) | ((u32)f2bf(mx1) << 16);
      const u32 pn = (u32)f2bf(mn0) | ((u32)f2bf(mn1) << 16);
      *(u32*)&wmaxo[pbase + (size_t)n*32 + cg*2] = pm;
      *(u32*)&wmino[pbase + (size_t)n*32 + cg*2] = pn;
    }
  }

  s0 += __shfl_xor(s0,16); s0 += __shfl_xor(s0,32);
  s1 += __shfl_xor(s1,16); s1 += __shfl_xor(s1,32);
  q0 += __shfl_xor(q0,16); q0 += __shfl_xor(q0,32);
  q1 += __shfl_xor(q1,16); q1 += __shfl_xor(q1,32);
  if (lane < 16){
    redS[wid][cg*2]   = s0;  redS[wid][cg*2+1] = s1;
    redQ[wid][cg*2]   = q0;  redQ[wid][cg*2+1] = q1;
  }
  __syncthreads();
  if (tid < 32){
    atomicAdd(&stats[h*32 + tid], redS[0][tid]+redS[1][tid]+redS[2][tid]+redS[3][tid]);
  } else if (tid < 64){
    const int c2 = tid - 32;
    atomicAdd(&stats[64 + h*32 + c2], redQ[0][c2]+redQ[1][c2]+redQ[2][c2]+redQ[3][c2]);
  }
}

// ---------------- K4 v4: v2 structure + rotated stride-64 hl, b64 reads ----------
// ONLY change vs v2: hl stored as [ml][(c + 4*ml) & 63] stride 64; B-fragment
// reads = 2x ds_read_b64 per chunk at 16 even start banks (~4-way, b64 floor)
// instead of 8-way-conflicted ds_read_b128 at stride 144B.
__global__ __launch_bounds__(256) void k4_mfma(const u16* __restrict__ wmaxo,
                                               const u16* __restrict__ wmino,
                                               const float* __restrict__ stats,
                                               const float* __restrict__ gamma,
                                               const float* __restrict__ beta,
                                               const float* __restrict__ coords,
                                               const u16* __restrict__ wbf,
                                               const float* __restrict__ bconv,
                                               float* __restrict__ out){
  const int n0 = blockIdx.x * 64;
  const int b  = blockIdx.y;
  const int tid = threadIdx.x;
  const int w = tid >> 6, lane = tid & 63;
  const int r15 = lane & 15, kg = lane >> 4;

  __shared__ __align__(16) u16 hl[72*64];   // rotated, stride 64 -> 9.2 KB
  __shared__ float wgt[9*64];   // [j][n] Gaussian weights
  __shared__ float sctl[128];   // BN affine

  if (tid < 64){
    const float inv = 1.0f / (float)(B_*N_*K_);
    const float mean = stats[tid] * inv;
    const float var  = stats[64+tid] * inv - mean*mean;
    const float s = gamma[tid] * rsqrtf(var + EPSBN);
    sctl[tid] = s;
    sctl[64+tid] = beta[tid] - mean*s;
  }
  __syncthreads();

  // hbn tile build: rows m = n0-4 .. n0+67, rotated storage
  {
    const int c = tid & 63;
    const float s = sctl[c], t = sctl[64+c];
    const u16* src = ((s >= 0.f) ? wmaxo : wmino)
                   + ((size_t)((c >> 5)*B_ + b))*N_*32 + (c & 31);
    #pragma unroll
    for (int it = 0; it < 18; ++it){
      const int ml = (tid >> 6) + it*4;
      const int m = n0 - 4 + ml;
      float hv = 0.f;
      if (m >= 0 && m < N_){
        hv = fmaf(s, bf2f(src[(size_t)m*32]), t);
        hv = (hv >= 0.f) ? hv : NEG*hv;
      }
      hl[ml*64 + ((c + 4*ml) & 63)] = f2bf(hv);
    }
  }
  for (int idx = tid; idx < 576; idx += 256){
    const int j = idx >> 6, n = idx & 63;
    const int mc = n0 + n, mt = mc + j - 4;
    float wv = 0.f;
    if (mt >= 0 && mt < N_){
      float d2 = 0.f;
      #pragma unroll
      for (int d = 0; d < 3; ++d){
        const float dd = coords[(b*3+d)*N_ + mt] - coords[(b*3+d)*N_ + mc];
        d2 = fmaf(dd, dd, d2);
      }
      wv = __expf(-INV_SIG2 * d2);
    }
    wgt[idx] = wv;
  }
  __syncthreads();

  const u16* abase = wbf + ((w*32 + r15)*64 + kg*8);   // + j*8192 + of*1024 + kh*32
  f32x4 acc[2][4] = {};
  const f32x4 zero = {0.f, 0.f, 0.f, 0.f};

  for (int j = 0; j < 9; ++j){
    float wj[4];
    #pragma unroll
    for (int nf = 0; nf < 4; ++nf) wj[nf] = wgt[j*64 + nf*16 + r15];
    short8 bfr[4][2];
    #pragma unroll
    for (int nf = 0; nf < 4; ++nf){
      const int row = r15 + nf*16 + j;
      const int rb = row*64;
      const int r4 = (row*4) & 63;
      #pragma unroll
      for (int kh = 0; kh < 2; ++kh){
        const int cb = kg*8 + kh*32;
        const uint2 g0 = *(const uint2*)&hl[rb + ((cb     + r4) & 63)];
        const uint2 g1 = *(const uint2*)&hl[rb + ((cb + 4 + r4) & 63)];
        union { short8 s; u32 u[4]; } bb;
        bb.u[0] = g0.x; bb.u[1] = g0.y; bb.u[2] = g1.x; bb.u[3] = g1.y;
        bfr[nf][kh] = bb.s;
      }
    }
    #pragma unroll
    for (int of = 0; of < 2; ++of){
      const short8 a0 = *(const short8*)&abase[j*8192 + of*1024];
      const short8 a1 = *(const short8*)&abase[j*8192 + of*1024 + 32];
      #pragma unroll
      for (int nf = 0; nf < 4; ++nf){
        f32x4 p = __builtin_amdgcn_mfma_f32_16x16x32_bf16(a0, bfr[nf][0], zero, 0, 0, 0);
        p = __builtin_amdgcn_mfma_f32_16x16x32_bf16(a1, bfr[nf][1], p, 0, 0, 0);
        #pragma unroll
        for (int r = 0; r < 4; ++r)
          acc[of][nf][r] = fmaf(wj[nf], p[r], acc[of][nf][r]);
      }
    }
  }

  #pragma unroll
  for (int of = 0; of < 2; ++of){
    #pragma unroll
    for (int r = 0; r < 4; ++r){
      const int o = w*32 + of*16 + kg*4 + r;
      const float bs = bconv[o];
      float* dst = &out[(size_t)(b*128 + o)*N_ + n0 + r15];
      #pragma unroll
      for (int nf = 0; nf < 4; ++nf)
        dst[nf*16] = acc[of][nf][r] + bs;
    }
  }
}

extern "C" void kernel_launch(void* const* d_in, const int* in_sizes, int n_in,
                              void* d_out, int out_size, void* d_ws, size_t ws_size,
                              hipStream_t stream){
  const float* x      = (const float*)d_in[0];
  const float* coords = (const float*)d_in[1];
  const int*   eidx   = (const int*)  d_in[2];
  const float* we     = (const float*)d_in[3];
  const float* gamma  = (const float*)d_in[4];
  const float* beta   = (const float*)d_in[5];
  const float* wconv  = (const float*)d_in[6];
  const float* bconv  = (const float*)d_in[7];
  float* out = (float*)d_out;
  char* ws = (char*)d_ws;
  // ws layout (bytes): u[8.39MB] v[8.39MB] wmax[8.39MB] wmin[8.39MB] stats[512]
  //                    (pad 512) wbf[147KB] weA[16KB]
  u16* u     = (u16*)(ws);
  u16* v     = (u16*)(ws + 8388608);
  u16* wmax_ = (u16*)(ws + 16777216);
  u16* wmin_ = (u16*)(ws + 25165824);
  float* stats = (float*)(ws + 33554432);
  u16* wbf     = (u16*)(ws + 33555456);
  u16* weA     = (u16*)(ws + 33555456 + 147456);

  k0_wprep<<<320, 256, 0, stream>>>(wconv, wbf, we, weA, stats);
  k1_uv<<<dim3(N_/64, B_), 256, 0, stream>>>(x, weA, u, v);
  k2_gather<<<4096, 256, 0, stream>>>(u, v, eidx, wmax_, wmin_, stats);
  k4_mfma<<<dim3(N_/64, B_), 256, 0, stream>>>(wmax_, wmin_, stats, gamma, beta,
                                               coords, wbf, bconv, out);
}

// Round 14
// 112.715 us; speedup vs baseline: 1.1562x; 1.0060x over previous
//
#include <hip/hip_runtime.h>
#include <hip/hip_bf16.h>

#define B_ 4
#define N_ 16384
#define K_ 16
#define NEG 0.2f
#define EPSBN 1e-5f
#define INV_SIG2 2500.0f

typedef unsigned short u16;
typedef unsigned int   u32;
typedef __attribute__((ext_vector_type(8))) short short8;
typedef __attribute__((ext_vector_type(4))) float f32x4;

__device__ __forceinline__ float bf2f(u16 h){
  return __uint_as_float(((u32)h) << 16);
}
__device__ __forceinline__ u16 f2bf(float f){
  u32 x = __float_as_uint(f);
  x += 0x7fffu + ((x >> 16) & 1u);
  return (u16)(x >> 16);
}

// u/v/wmax/wmin layout: split [half][B][N][32] u16 — (batch, channel-half)
// partition = 2MB u+v -> fits one XCD's 4MB L2.

// ---------------- K0: wbf [j][o][c]; weA [o][c]; zero stats ----------------------
__global__ void k0_wprep(const float* __restrict__ wconv, u16* __restrict__ wbf,
                         const float* __restrict__ we, u16* __restrict__ weA,
                         float* __restrict__ stats){
  const int idx = blockIdx.x * 256 + threadIdx.x;
  if (idx < 128) stats[idx] = 0.f;
  if (idx < 9*128*64){
    const int j = idx >> 13;
    const int rem = idx & 8191;
    const int o = rem >> 6, c = rem & 63;
    wbf[idx] = f2bf(wconv[(o*64 + c)*9 + j]);
  } else if (idx < 9*128*64 + 128*64){
    const int t = idx - 9*128*64;
    const int o = t >> 6, c = t & 63;
    float w;
    if (o < 64) w = we[o*128 + c] - we[o*128 + 64 + c];
    else        w = we[(o-64)*128 + 64 + c];
    weA[t] = f2bf(w);
  }
}

// ---------------- K1 v2: MFMA GEMM [u;v](128 x n) = weA(128x64) * x(64 x n) ------
__global__ __launch_bounds__(256) void k1_uv(const float* __restrict__ x,
                                             const u16* __restrict__ weA,
                                             u16* __restrict__ uo,
                                             u16* __restrict__ vo){
  const int n0 = blockIdx.x * 64;
  const int b  = blockIdx.y;
  const int tid = threadIdx.x;
  const int w = tid >> 6, lane = tid & 63;
  const int r15 = lane & 15, kg = lane >> 4;

  __shared__ u16 tl[128*72];   // [o][n] stride 72 -> 18.4 KB

  short8 a[2][2];
  #pragma unroll
  for (int of = 0; of < 2; ++of)
    #pragma unroll
    for (int kh = 0; kh < 2; ++kh)
      a[of][kh] = *(const short8*)&weA[(w*32 + of*16 + r15)*64 + kg*8 + kh*32];

  const float* xb = x + (size_t)b*64*N_ + n0 + r15;
  f32x4 acc[2][4];
  const f32x4 zero = {0.f, 0.f, 0.f, 0.f};

  #pragma unroll
  for (int nf = 0; nf < 4; ++nf){
    short8 bq[2];
    #pragma unroll
    for (int kh = 0; kh < 2; ++kh){
      float f[8];
      #pragma unroll
      for (int e = 0; e < 8; ++e)
        f[e] = xb[(size_t)(kg*8 + kh*32 + e)*N_ + nf*16];
      union { short8 s; u32 u[4]; } bb;
      #pragma unroll
      for (int e2 = 0; e2 < 4; ++e2)
        bb.u[e2] = (u32)f2bf(f[e2*2]) | ((u32)f2bf(f[e2*2+1]) << 16);
      bq[kh] = bb.s;
    }
    #pragma unroll
    for (int of = 0; of < 2; ++of){
      f32x4 p = __builtin_amdgcn_mfma_f32_16x16x32_bf16(a[of][0], bq[0], zero, 0, 0, 0);
      acc[of][nf] = __builtin_amdgcn_mfma_f32_16x16x32_bf16(a[of][1], bq[1], p, 0, 0, 0);
    }
  }

  #pragma unroll
  for (int of = 0; of < 2; ++of)
    #pragma unroll
    for (int rr = 0; rr < 4; ++rr){
      const int o = w*32 + of*16 + kg*4 + rr;
      #pragma unroll
      for (int nf = 0; nf < 4; ++nf)
        tl[o*72 + nf*16 + r15] = f2bf(acc[of][nf][rr]);
    }
  __syncthreads();

  const int arr = tid >> 7, half = (tid >> 6) & 1, n = tid & 63;
  const int ro = arr*64 + half*32;
  u32 pk[16];
  #pragma unroll
  for (int cc = 0; cc < 16; ++cc){
    const u16 lo = tl[(ro + cc*2    )*72 + n];
    const u16 hi = tl[(ro + cc*2 + 1)*72 + n];
    pk[cc] = (u32)lo | ((u32)hi << 16);
  }
  u16* dst = (arr ? vo : uo) + ((size_t)(half*B_ + b)*N_ + n0 + n)*32;
  *(uint4*)(dst +  0) = make_uint4(pk[0],  pk[1],  pk[2],  pk[3]);
  *(uint4*)(dst +  8) = make_uint4(pk[4],  pk[5],  pk[6],  pk[7]);
  *(uint4*)(dst + 16) = make_uint4(pk[8],  pk[9],  pk[10], pk[11]);
  *(uint4*)(dst + 24) = make_uint4(pk[12], pk[13], pk[14], pk[15]);
}

// ---------------- K2 v8 (round-9 best, unchanged) --------------------------------
__global__ __launch_bounds__(256) void k2_gather(const u16* __restrict__ uo,
                                                 const u16* __restrict__ vo,
                                                 const int* __restrict__ eidx,
                                                 u16* __restrict__ wmaxo,
                                                 u16* __restrict__ wmino,
                                                 float* __restrict__ stats){
  const int bid = blockIdx.x;
  const int p8  = bid & 7;
  const int b   = p8 >> 1;
  const int h   = p8 & 1;
  const int n0  = (bid >> 3) * 32;
  const int tid = threadIdx.x;
  const int wid = tid >> 6, lane = tid & 63;
  const int kk = lane >> 4, cg = lane & 15;
  const int nb = n0 + wid*8;                 // wave's 8 points
  const size_t pbase = ((size_t)(h*B_ + b))*N_*32;
  const u16* ub = uo + pbase;
  const u16* vb = vo + pbase;

  __shared__ int eL[4][2][128];              // per-wave eidx copy (4KB)
  __shared__ float redS[4][32], redQ[4][32];

  const int* e0 = eidx + (b*N_ + nb)*K_;               // j (neighbor -> v)
  const int* e1 = eidx + B_*N_*K_ + (b*N_ + nb)*K_;    // i (center   -> u)
  if (lane < 32) *(int4*)&eL[wid][0][lane*4]      = *(const int4*)(e0 + lane*4);
  else           *(int4*)&eL[wid][1][(lane-32)*4] = *(const int4*)(e1 + (lane-32)*4);
  __syncthreads();

  float s0=0.f, s1=0.f, q0=0.f, q1=0.f;

  for (int p = 0; p < 8; ++p){
    int ji[4], ii[4];
    #pragma unroll
    for (int s = 0; s < 4; ++s){
      ji[s] = eL[wid][0][p*16 + s*4 + kk];
      ii[s] = eL[wid][1][p*16 + s*4 + kk];
    }
    u32 ua[4], va[4];
    #pragma unroll
    for (int s = 0; s < 4; ++s){
      ua[s] = *(const u32*)&ub[(size_t)ii[s]*32 + cg*2];
      va[s] = *(const u32*)&vb[(size_t)ji[s]*32 + cg*2];
    }
    float hL[4], hH[4];
    #pragma unroll
    for (int s = 0; s < 4; ++s){
      hL[s] = __uint_as_float(ua[s] << 16)         + __uint_as_float(va[s] << 16);
      hH[s] = __uint_as_float(ua[s] & 0xffff0000u) + __uint_as_float(va[s] & 0xffff0000u);
    }
    float mx0 = fmaxf(fmaxf(hL[0],hL[1]), fmaxf(hL[2],hL[3]));
    float mn0 = fminf(fminf(hL[0],hL[1]), fminf(hL[2],hL[3]));
    float mx1 = fmaxf(fmaxf(hH[0],hH[1]), fmaxf(hH[2],hH[3]));
    float mn1 = fminf(fminf(hH[0],hH[1]), fminf(hH[2],hH[3]));
    s0 += (hL[0]+hL[1]) + (hL[2]+hL[3]);
    s1 += (hH[0]+hH[1]) + (hH[2]+hH[3]);
    q0 = fmaf(hL[0],hL[0], fmaf(hL[1],hL[1], fmaf(hL[2],hL[2], fmaf(hL[3],hL[3], q0))));
    q1 = fmaf(hH[0],hH[0], fmaf(hH[1],hH[1], fmaf(hH[2],hH[2], fmaf(hH[3],hH[3], q1))));
    mx0 = fmaxf(mx0, __shfl_xor(mx0, 16)); mx0 = fmaxf(mx0, __shfl_xor(mx0, 32));
    mx1 = fmaxf(mx1, __shfl_xor(mx1, 16)); mx1 = fmaxf(mx1, __shfl_xor(mx1, 32));
    mn0 = fminf(mn0, __shfl_xor(mn0, 16)); mn0 = fminf(mn0, __shfl_xor(mn0, 32));
    mn1 = fminf(mn1, __shfl_xor(mn1, 16)); mn1 = fminf(mn1, __shfl_xor(mn1, 32));
    const int n = nb + p;
    if (lane < 16){
      const u32 pm = (u32)f2bf(mx0) | ((u32)f2bf(mx1) << 16);
      const u32 pn = (u32)f2bf(mn0) | ((u32)f2bf(mn1) << 16);
      *(u32*)&wmaxo[pbase + (size_t)n*32 + cg*2] = pm;
      *(u32*)&wmino[pbase + (size_t)n*32 + cg*2] = pn;
    }
  }

  s0 += __shfl_xor(s0,16); s0 += __shfl_xor(s0,32);
  s1 += __shfl_xor(s1,16); s1 += __shfl_xor(s1,32);
  q0 += __shfl_xor(q0,16); q0 += __shfl_xor(q0,32);
  q1 += __shfl_xor(q1,16); q1 += __shfl_xor(q1,32);
  if (lane < 16){
    redS[wid][cg*2]   = s0;  redS[wid][cg*2+1] = s1;
    redQ[wid][cg*2]   = q0;  redQ[wid][cg*2+1] = q1;
  }
  __syncthreads();
  if (tid < 32){
    atomicAdd(&stats[h*32 + tid], redS[0][tid]+redS[1][tid]+redS[2][tid]+redS[3][tid]);
  } else if (tid < 64){
    const int c2 = tid - 32;
    atomicAdd(&stats[64 + h*32 + c2], redQ[0][c2]+redQ[1][c2]+redQ[2][c2]+redQ[3][c2]);
  }
}

// ---------------- K4 v5: v4 + fully-unrolled j-loop, VGPR cap 128 ----------------
// Full unroll exposes all 36 A-loads + 144 ds_reads to the scheduler for
// software pipelining; __launch_bounds__(256,4) caps VGPR at 128 so the
// 4-blocks/CU occupancy of grid 1024 is preserved (r4/r10 failure mode guard).
__global__ __launch_bounds__(256, 4) void k4_mfma(const u16* __restrict__ wmaxo,
                                                  const u16* __restrict__ wmino,
                                                  const float* __restrict__ stats,
                                                  const float* __restrict__ gamma,
                                                  const float* __restrict__ beta,
                                                  const float* __restrict__ coords,
                                                  const u16* __restrict__ wbf,
                                                  const float* __restrict__ bconv,
                                                  float* __restrict__ out){
  const int n0 = blockIdx.x * 64;
  const int b  = blockIdx.y;
  const int tid = threadIdx.x;
  const int w = tid >> 6, lane = tid & 63;
  const int r15 = lane & 15, kg = lane >> 4;

  __shared__ __align__(16) u16 hl[72*64];   // rotated, stride 64 -> 9.2 KB
  __shared__ float wgt[9*64];   // [j][n] Gaussian weights
  __shared__ float sctl[128];   // BN affine

  if (tid < 64){
    const float inv = 1.0f / (float)(B_*N_*K_);
    const float mean = stats[tid] * inv;
    const float var  = stats[64+tid] * inv - mean*mean;
    const float s = gamma[tid] * rsqrtf(var + EPSBN);
    sctl[tid] = s;
    sctl[64+tid] = beta[tid] - mean*s;
  }
  __syncthreads();

  // hbn tile build: rows m = n0-4 .. n0+67, rotated storage
  {
    const int c = tid & 63;
    const float s = sctl[c], t = sctl[64+c];
    const u16* src = ((s >= 0.f) ? wmaxo : wmino)
                   + ((size_t)((c >> 5)*B_ + b))*N_*32 + (c & 31);
    #pragma unroll
    for (int it = 0; it < 18; ++it){
      const int ml = (tid >> 6) + it*4;
      const int m = n0 - 4 + ml;
      float hv = 0.f;
      if (m >= 0 && m < N_){
        hv = fmaf(s, bf2f(src[(size_t)m*32]), t);
        hv = (hv >= 0.f) ? hv : NEG*hv;
      }
      hl[ml*64 + ((c + 4*ml) & 63)] = f2bf(hv);
    }
  }
  for (int idx = tid; idx < 576; idx += 256){
    const int j = idx >> 6, n = idx & 63;
    const int mc = n0 + n, mt = mc + j - 4;
    float wv = 0.f;
    if (mt >= 0 && mt < N_){
      float d2 = 0.f;
      #pragma unroll
      for (int d = 0; d < 3; ++d){
        const float dd = coords[(b*3+d)*N_ + mt] - coords[(b*3+d)*N_ + mc];
        d2 = fmaf(dd, dd, d2);
      }
      wv = __expf(-INV_SIG2 * d2);
    }
    wgt[idx] = wv;
  }
  __syncthreads();

  const u16* abase = wbf + ((w*32 + r15)*64 + kg*8);   // + j*8192 + of*1024 + kh*32
  f32x4 acc[2][4] = {};
  const f32x4 zero = {0.f, 0.f, 0.f, 0.f};

  #pragma unroll
  for (int j = 0; j < 9; ++j){
    float wj[4];
    #pragma unroll
    for (int nf = 0; nf < 4; ++nf) wj[nf] = wgt[j*64 + nf*16 + r15];
    short8 bfr[4][2];
    #pragma unroll
    for (int nf = 0; nf < 4; ++nf){
      const int row = r15 + nf*16 + j;
      const int rb = row*64;
      const int r4 = (row*4) & 63;
      #pragma unroll
      for (int kh = 0; kh < 2; ++kh){
        const int cb = kg*8 + kh*32;
        const uint2 g0 = *(const uint2*)&hl[rb + ((cb     + r4) & 63)];
        const uint2 g1 = *(const uint2*)&hl[rb + ((cb + 4 + r4) & 63)];
        union { short8 s; u32 u[4]; } bb;
        bb.u[0] = g0.x; bb.u[1] = g0.y; bb.u[2] = g1.x; bb.u[3] = g1.y;
        bfr[nf][kh] = bb.s;
      }
    }
    #pragma unroll
    for (int of = 0; of < 2; ++of){
      const short8 a0 = *(const short8*)&abase[j*8192 + of*1024];
      const short8 a1 = *(const short8*)&abase[j*8192 + of*1024 + 32];
      #pragma unroll
      for (int nf = 0; nf < 4; ++nf){
        f32x4 p = __builtin_amdgcn_mfma_f32_16x16x32_bf16(a0, bfr[nf][0], zero, 0, 0, 0);
        p = __builtin_amdgcn_mfma_f32_16x16x32_bf16(a1, bfr[nf][1], p, 0, 0, 0);
        #pragma unroll
        for (int r = 0; r < 4; ++r)
          acc[of][nf][r] = fmaf(wj[nf], p[r], acc[of][nf][r]);
      }
    }
  }

  #pragma unroll
  for (int of = 0; of < 2; ++of){
    #pragma unroll
    for (int r = 0; r < 4; ++r){
      const int o = w*32 + of*16 + kg*4 + r;
      const float bs = bconv[o];
      float* dst = &out[(size_t)(b*128 + o)*N_ + n0 + r15];
      #pragma unroll
      for (int nf = 0; nf < 4; ++nf)
        dst[nf*16] = acc[of][nf][r] + bs;
    }
  }
}

extern "C" void kernel_launch(void* const* d_in, const int* in_sizes, int n_in,
                              void* d_out, int out_size, void* d_ws, size_t ws_size,
                              hipStream_t stream){
  const float* x      = (const float*)d_in[0];
  const float* coords = (const float*)d_in[1];
  const int*   eidx   = (const int*)  d_in[2];
  const float* we     = (const float*)d_in[3];
  const float* gamma  = (const float*)d_in[4];
  const float* beta   = (const float*)d_in[5];
  const float* wconv  = (const float*)d_in[6];
  const float* bconv  = (const float*)d_in[7];
  float* out = (float*)d_out;
  char* ws = (char*)d_ws;
  // ws layout (bytes): u[8.39MB] v[8.39MB] wmax[8.39MB] wmin[8.39MB] stats[512]
  //                    (pad 512) wbf[147KB] weA[16KB]
  u16* u     = (u16*)(ws);
  u16* v     = (u16*)(ws + 8388608);
  u16* wmax_ = (u16*)(ws + 16777216);
  u16* wmin_ = (u16*)(ws + 25165824);
  float* stats = (float*)(ws + 33554432);
  u16* wbf     = (u16*)(ws + 33555456);
  u16* weA     = (u16*)(ws + 33555456 + 147456);

  k0_wprep<<<320, 256, 0, stream>>>(wconv, wbf, we, weA, stats);
  k1_uv<<<dim3(N_/64, B_), 256, 0, stream>>>(x, weA, u, v);
  k2_gather<<<4096, 256, 0, stream>>>(u, v, eidx, wmax_, wmin_, stats);
  k4_mfma<<<dim3(N_/64, B_), 256, 0, stream>>>(wmax_, wmin_, stats, gamma, beta,
                                               coords, wbf, bconv, out);
}